// Round 3
// baseline (633.374 us; speedup 1.0000x reference)
//
#include <hip/hip_runtime.h>
#include <math.h>

#define NN 4096
#define ALPHA 0.1f
#define DT 0.01f
#define DIFF 10.0f
#define EPS 1e-9f
#define HB 1.5707963267948966f

// Per-step constants (8 floats = 2 float4), in GLOBAL scratch:
//  q0 = (ci, si, axx, ayy)   q1 = (xlo, xhi, ylo, yhi)
// Scan recurrence (wave-uniform, all lanes redundant):
//  xd = ci*U + si*V + axx ; yd = si*U - ci*V + ayy
//  dx = DT*clamp(xd,xlo,xhi) ; dy = DT*clamp(yd,ylo,yhi)
//  U += ci*dx + si*dy ; V += si*dx - ci*dy
//  y_new_i = yi + dy   (lane (i&63) keeps dy for the coalesced flush)

__global__ void prep_kernel(const float* __restrict__ phase,
                            const float* __restrict__ w,
                            const float* __restrict__ ha,
                            const float* __restrict__ xy,
                            const float* __restrict__ xydo,
                            float* __restrict__ st,
                            float* __restrict__ partials) {
  int i = blockIdx.x * blockDim.x + threadIdx.x;
  float ph = phase[i];
  float ci = cosf(ph), si = sinf(ph);
  float2 p = reinterpret_cast<const float2*>(xy)[i];
  float2 d = reinterpret_cast<const float2*>(xydo)[i];
  float r2 = fmaf(p.x, p.x, p.y * p.y);
  float ta = ALPHA * (1.f - r2 * r2);
  float zeta = 1.f - ha[i] * ((d.x + EPS) / (fabsf(d.x) + EPS));
  float tb = w[i] / (zeta + EPS);
  float4 q0 = make_float4(ci, si, ta * p.x - tb * p.y - p.x,
                          tb * p.x + ta * p.y - p.y);
  float4 q1 = make_float4(d.x - DIFF, d.x + DIFF, d.y - DIFF, d.y + DIFF);
  float4* stq = (float4*)st;
  stq[i * 2 + 0] = q0;
  stq[i * 2 + 1] = q1;

  // block-partial of U = sum(cj*xj + sj*yj), V = sum(sj*xj - cj*yj)
  float u = fmaf(ci, p.x, si * p.y);
  float v = fmaf(si, p.x, -ci * p.y);
#pragma unroll
  for (int off = 32; off; off >>= 1) {
    u += __shfl_xor(u, off, 64);
    v += __shfl_xor(v, off, 64);
  }
  __shared__ float su[4], sv[4];
  int wid = threadIdx.x >> 6;
  if ((threadIdx.x & 63) == 0) { su[wid] = u; sv[wid] = v; }
  __syncthreads();
  if (threadIdx.x == 0) {
    partials[blockIdx.x]      = (su[0] + su[1]) + (su[2] + su[3]);
    partials[16 + blockIdx.x] = (sv[0] + sv[1]) + (sv[2] + sv[3]);
  }
}

#define FENCE __builtin_amdgcn_sched_barrier(0)

#define LOADG(P, gidx) do {                                    \
    const float4* _b = qbase + (size_t)(gidx) * 8;             \
    P##0 = _b[0]; P##1 = _b[1]; P##2 = _b[2]; P##3 = _b[3];    \
    P##4 = _b[4]; P##5 = _b[5]; P##6 = _b[6]; P##7 = _b[7];    \
  } while (0)

#define STEP1(q0, q1, sidx) do {                               \
    float xd = fmaf(q0.x, U, fmaf(q0.y, V, q0.z));             \
    float yd = fmaf(q0.y, U, fmaf(-q0.x, V, q0.w));            \
    float dx = DT * fminf(fmaxf(xd, q1.x), q1.y);              \
    float dy = DT * fminf(fmaxf(yd, q1.z), q1.w);              \
    U = fmaf(q0.x, dx, fmaf(q0.y, dy, U));                     \
    V = fmaf(q0.y, dx, fmaf(-q0.x, dy, V));                    \
    dyk = (((sidx) & 63) == lane) ? dy : dyk;                  \
  } while (0)

#define STEPS(P, g) do {                                       \
    STEP1(P##0, P##1, (g) * 4 + 0);                            \
    STEP1(P##2, P##3, (g) * 4 + 1);                            \
    STEP1(P##4, P##5, (g) * 4 + 2);                            \
    STEP1(P##6, P##7, (g) * 4 + 3);                            \
  } while (0)

__global__ __launch_bounds__(64, 1) void scan_kernel(
    const float* __restrict__ st, const float* __restrict__ partials,
    const float* __restrict__ amp, const float* __restrict__ bvec,
    const float* __restrict__ xy, float* __restrict__ out) {
  const int lane = threadIdx.x;
  const float2* xy2 = (const float2*)xy;
  const float4* qbase = (const float4*)st;

  // ---- initial U,V from 16 block-partials ----
  float pu = (lane < 16) ? partials[lane] : 0.f;
  float pv = (lane < 16) ? partials[16 + lane] : 0.f;
#pragma unroll
  for (int off = 32; off; off >>= 1) {
    pu += __shfl_xor(pu, off, 64);
    pv += __shfl_xor(pv, off, 64);
  }
  float U = pu, V = pv;   // identical across lanes
  float dyk = 0.f;

  // per-64-step output params for block 0
  float ampC = amp[lane];
  float bbC  = bvec[lane];
  float yiC  = xy2[lane].y;

  float4 A0, A1, A2, A3, A4, A5, A6, A7;
  float4 B0, B1, B2, B3, B4, B5, B6, B7;
  float4 C0, C1, C2, C3, C4, C5, C6, C7;
  float4 Dd0, Dd1, Dd2, Dd3, Dd4, Dd5, Dd6, Dd7;

  LOADG(A, 0);
  LOADG(B, 1);
  LOADG(C, 2);
  FENCE;

  for (int si_ = 0; si_ < 256; ++si_) {
    int g = si_ * 4;
    LOADG(Dd, g + 3); FENCE; STEPS(A, g);
    LOADG(A, g + 4);  FENCE; STEPS(B, g + 1);
    LOADG(B, g + 5);  FENCE; STEPS(C, g + 2);
    LOADG(C, g + 6);  FENCE; STEPS(Dd, g + 3);
    // loads at g+4..g+6 overrun past group 1023 on the last iters;
    // they land in workspace slack and are never consumed.

    if ((si_ & 3) == 3) {   // flush one 64-step block (coalesced)
      int blk = si_ >> 2;
      int gb = blk * 64 + lane;
      float ang = fmaf(ampC, yiC + dyk, bbC);
      out[gb] = fminf(fmaxf(ang, -HB), HB);
      int nb = ((blk + 1 < 64) ? blk + 1 : 63) * 64 + lane;
      ampC = amp[nb];
      bbC  = bvec[nb];
      yiC  = xy2[nb].y;
    }
  }
}

extern "C" void kernel_launch(void* const* d_in, const int* in_sizes, int n_in,
                              void* d_out, int out_size, void* d_ws, size_t ws_size,
                              hipStream_t stream) {
  const float* phase = (const float*)d_in[0];
  const float* amp   = (const float*)d_in[1];
  const float* w     = (const float*)d_in[2];
  const float* ha    = (const float*)d_in[3];
  const float* b     = (const float*)d_in[4];
  const float* xy    = (const float*)d_in[5];
  const float* xydo  = (const float*)d_in[6];
  float* out = (float*)d_out;

  float* partials = (float*)d_ws;                 // 32 floats
  float* st = (float*)((char*)d_ws + 256);        // NN*8 floats + slack

  prep_kernel<<<16, 256, 0, stream>>>(phase, w, ha, xy, xydo, st, partials);
  scan_kernel<<<1, 64, 0, stream>>>(st, partials, amp, b, xy, out);
}

// Round 5
// 277.613 us; speedup vs baseline: 2.2815x; 2.2815x over previous
//
#include <hip/hip_runtime.h>
#include <math.h>

#define NN 4096
#define ALPHA 0.1f
#define DT 0.01f
#define DIFF 10.0f
#define EPS 1e-9f
#define HB 1.5707963267948966f
#define CHUNK 2048              // steps per LDS fill (2048 * 32 B = 64 KB)
#define PAIRS (CHUNK / 2)       // 2-step groups per chunk

typedef float f32x4 __attribute__((ext_vector_type(4)));

#define FENCE __builtin_amdgcn_sched_barrier(0)

// Load one PAIR of steps (4 x f32x4) into named registers. Plain C++ LDS
// reads -> ds_read_b128; FENCE after each group pins placement so the
// scheduler cannot sink them to their uses (R2 failure mode).
#define LOADP(P, p) do {                                      \
    const f32x4* _q = lds4 + (((p) & (PAIRS - 1)) << 2);      \
    P##0 = _q[0]; P##1 = _q[1]; P##2 = _q[2]; P##3 = _q[3];   \
  } while (0)

// One scan step. q0=(ci,si,axx,ayy) q1=(xlo,xhi,ylo,yhi). kk = compile-time
// local step index within the current 64-step block; lb = lane - block_base.
//  xd = ci*U + si*V + axx ; yd = si*U - ci*V + ayy
//  cx = med3(xd,xlo,xhi) ; cy = med3(yd,ylo,yhi)  (bounds satisfy lo<hi)
//  U += ci*(DT*cx) + si*(DT*cy) ; V += si*(DT*cx) - ci*(DT*cy)
#define STEP1(q0, q1, kk) do {                                \
    float xd = fmaf(q0.x, U, fmaf(q0.y, V, q0.z));            \
    float yd = fmaf(q0.y, U, fmaf(-q0.x, V, q0.w));           \
    float cx = __builtin_amdgcn_fmed3f(xd, q1.x, q1.y);       \
    float cy = __builtin_amdgcn_fmed3f(yd, q1.z, q1.w);       \
    float dx = cx * DT, dy = cy * DT;                         \
    U = fmaf(q0.x, dx, fmaf(q0.y, dy, U));                    \
    V = fmaf(q0.y, dx, fmaf(-q0.x, dy, V));                   \
    cyk = ((kk) == lb) ? cy : cyk;                            \
  } while (0)

#define STEPP(P, k0) do { STEP1(P##0, P##1, k0); STEP1(P##2, P##3, (k0) + 1); } while (0)

__global__ __launch_bounds__(64, 1) void cpg_kernel(
    const float* __restrict__ phase, const float* __restrict__ amp,
    const float* __restrict__ w, const float* __restrict__ ha,
    const float* __restrict__ bvec, const float* __restrict__ xy,
    const float* __restrict__ xydo, float* __restrict__ out) {
  __shared__ f32x4 st[CHUNK * 2];   // 64 KB: one chunk of step-constants
  const int lane = threadIdx.x;
  const float2* xy2 = (const float2*)xy;
  const float2* xd2 = (const float2*)xydo;
  const f32x4* lds4 = st;

  // ---- initial U = sum(cj*xj + sj*yj), V = sum(sj*xj - cj*yj) ----
  float u = 0.f, v = 0.f;
#pragma unroll 8
  for (int it = 0; it < NN / 64; ++it) {
    int i = it * 64 + lane;
    float s_, c_;
    sincosf(phase[i], &s_, &c_);
    float2 p = xy2[i];
    u = fmaf(c_, p.x, fmaf(s_, p.y, u));
    v = fmaf(s_, p.x, fmaf(-c_, p.y, v));
  }
#pragma unroll
  for (int off = 32; off; off >>= 1) {
    u += __shfl_xor(u, off, 64);
    v += __shfl_xor(v, off, 64);
  }
  float U = u, V = v;   // identical across lanes
  float cyk = 0.f;
  int tgt = lane;       // output index this lane owns next
  float ampC = amp[lane], bbC = bvec[lane], yiC = xy2[lane].y;

  for (int c = 0; c < NN / CHUNK; ++c) {
    __syncthreads();
    // ---- prep chunk c: fold per-step constants into LDS ----
#pragma unroll 4
    for (int it2 = 0; it2 < CHUNK / 64; ++it2) {
      int s = it2 * 64 + lane;
      int i = c * CHUNK + s;
      float s_, c_;
      sincosf(phase[i], &s_, &c_);
      float2 p = xy2[i];
      float2 d = xd2[i];
      float r2 = fmaf(p.x, p.x, p.y * p.y);
      float ta = ALPHA * (1.f - r2 * r2);
      float zeta = 1.f - ha[i] * ((d.x + EPS) / (fabsf(d.x) + EPS));
      float tb = w[i] / (zeta + EPS);
      f32x4 q0 = {c_, s_, ta * p.x - tb * p.y - p.x, tb * p.x + ta * p.y - p.y};
      f32x4 q1 = {d.x - DIFF, d.x + DIFF, d.y - DIFF, d.y + DIFF};
      st[s * 2 + 0] = q0;
      st[s * 2 + 1] = q1;
    }
    __syncthreads();

    // ---- scan chunk: 2-step groups, 4 rotating register buffers,
    //      prefetch distance 3 groups (12 ds_reads in flight <= 15 cap) ----
    f32x4 A0, A1, A2, A3, B0, B1, B2, B3;
    f32x4 C0, C1, C2, C3, D0, D1, D2, D3;
    LOADP(A, 0); LOADP(B, 1); LOADP(C, 2);
    FENCE;
    for (int it = 0; it < CHUNK / 8; ++it) {   // 8 steps per iteration
      int p = it * 4;
      int lb = lane - ((it & 7) << 3);         // owner-select base for this iter
      LOADP(D, p + 3); FENCE; STEPP(A, 0);
      LOADP(A, p + 4); FENCE; STEPP(B, 2);
      LOADP(B, p + 5); FENCE; STEPP(C, 4);
      LOADP(C, p + 6); FENCE; STEPP(D, 6);
      // (p+4..p+6 wrap at chunk end via &-mask: stale reads into regs that the
      //  next chunk's prologue overwrites before any use)
      if ((it & 7) == 7) {   // flush one 64-step block (coalesced, fused epilogue)
        float yn = fmaf(DT, cyk, yiC);
        float ang = fmaf(ampC, yn, bbC);
        out[tgt] = fminf(fmaxf(ang, -HB), HB);
        tgt += 64;
        int nb = (tgt < NN) ? tgt : (NN - 64 + lane);
        ampC = amp[nb]; bbC = bvec[nb]; yiC = xy2[nb].y;
      }
    }
  }
}

extern "C" void kernel_launch(void* const* d_in, const int* in_sizes, int n_in,
                              void* d_out, int out_size, void* d_ws, size_t ws_size,
                              hipStream_t stream) {
  const float* phase = (const float*)d_in[0];
  const float* amp   = (const float*)d_in[1];
  const float* w     = (const float*)d_in[2];
  const float* ha    = (const float*)d_in[3];
  const float* b     = (const float*)d_in[4];
  const float* xy    = (const float*)d_in[5];
  const float* xydo  = (const float*)d_in[6];
  float* out = (float*)d_out;

  cpg_kernel<<<1, 64, 0, stream>>>(phase, amp, w, ha, b, xy, xydo, out);
}

// Round 6
// 242.936 us; speedup vs baseline: 2.6072x; 1.1427x over previous
//
#include <hip/hip_runtime.h>
#include <math.h>

#define NN 4096
#define ALPHA 0.1f
#define DT 0.01f
#define DIFF 10.0f
#define EPS 1e-9f
#define HB 1.5707963267948966f
#define CHUNK 2048               // steps per LDS fill (64 KB)
#define PAIRS (CHUNK / 2)        // 2-step groups, 64 B each

typedef float f32x4 __attribute__((ext_vector_type(4)));

#define SBAR __builtin_amdgcn_sched_barrier(0)
// counted wait: oldest in-flight group (4 reads) guaranteed retired
#define W12 do { asm volatile("s_waitcnt lgkmcnt(12)" ::: "memory"); SBAR; } while (0)
#define W0  do { asm volatile("s_waitcnt lgkmcnt(0)"  ::: "memory"); SBAR; } while (0)

// issue one pair-group (2 steps = 4 x b128) into named ext_vector registers;
// asm volatile keeps issue order among asm ops, ext_vector "=v" maps to a
// contiguous 4-VGPR tuple (R4's float4-class operands did not).
#define PRE(P, pairidx) do {                                               \
    unsigned _a = sbase + (((unsigned)(pairidx) & (PAIRS - 1u)) << 6);     \
    asm volatile("ds_read_b128 %0, %1 offset:0"  : "=v"(P##0) : "v"(_a));  \
    asm volatile("ds_read_b128 %0, %1 offset:16" : "=v"(P##1) : "v"(_a));  \
    asm volatile("ds_read_b128 %0, %1 offset:32" : "=v"(P##2) : "v"(_a));  \
    asm volatile("ds_read_b128 %0, %1 offset:48" : "=v"(P##3) : "v"(_a));  \
  } while (0)

// One scan step. q0=(ci,si,axx,ayy) q1=(xlo,xhi,ylo,yhi); bounds are finite
// with lo<hi so med3 == clamp.  kk = compile-time local step in 64-block.
#define STEP1(q0, q1, kk) do {                                 \
    float xd = fmaf(q0.x, U, fmaf(q0.y, V, q0.z));             \
    float yd = fmaf(q0.y, U, fmaf(-q0.x, V, q0.w));            \
    float cx = __builtin_amdgcn_fmed3f(xd, q1.x, q1.y);        \
    float cy = __builtin_amdgcn_fmed3f(yd, q1.z, q1.w);        \
    float dx = cx * DT, dy = cy * DT;                          \
    U = fmaf(q0.x, dx, fmaf(q0.y, dy, U));                     \
    V = fmaf(q0.y, dx, fmaf(-q0.x, dy, V));                    \
    cyk = (lane == (kk)) ? cy : cyk;                           \
  } while (0)

#define S2(P, kk) do { STEP1(P##0, P##1, kk); STEP1(P##2, P##3, (kk) + 1); } while (0)

__global__ __launch_bounds__(64, 1) void cpg_kernel(
    const float* __restrict__ phase, const float* __restrict__ amp,
    const float* __restrict__ w, const float* __restrict__ ha,
    const float* __restrict__ bvec, const float* __restrict__ xy,
    const float* __restrict__ xydo, float* __restrict__ out) {
  __shared__ f32x4 st[CHUNK * 2];   // 64 KB, single buffer, refilled per chunk
  const int lane = threadIdx.x;
  const float2* xy2 = (const float2*)xy;
  const float2* xd2 = (const float2*)xydo;
  // LDS byte offset of st: single static __shared__ object; flat->LDS
  // truncation (shared aperture low-32 is the LDS offset).
  unsigned sbase = (unsigned)(uintptr_t)&st[0];

  // ---- initial U = sum(cj*xj + sj*yj), V = sum(sj*xj - cj*yj) ----
  float u = 0.f, v = 0.f;
#pragma unroll 8
  for (int it = 0; it < NN / 64; ++it) {
    int i = it * 64 + lane;
    float s_, c_;
    sincosf(phase[i], &s_, &c_);
    float2 p = xy2[i];
    u = fmaf(c_, p.x, fmaf(s_, p.y, u));
    v = fmaf(s_, p.x, fmaf(-c_, p.y, v));
  }
#pragma unroll
  for (int off = 32; off; off >>= 1) {
    u += __shfl_xor(u, off, 64);
    v += __shfl_xor(v, off, 64);
  }
  float U = u, V = v;   // identical across lanes
  float cyk = 0.f;
  int tgt = lane;
  float ampC = amp[lane], bbC = bvec[lane], yiC = xy2[lane].y;

  for (int c = 0; c < NN / CHUNK; ++c) {
    __syncthreads();
    // ---- prep chunk c: fold per-step constants into LDS ----
#pragma unroll 4
    for (int it2 = 0; it2 < CHUNK / 64; ++it2) {
      int s = it2 * 64 + lane;
      int i = c * CHUNK + s;
      float s_, c_;
      sincosf(phase[i], &s_, &c_);
      float2 p = xy2[i];
      float2 d = xd2[i];
      float r2 = fmaf(p.x, p.x, p.y * p.y);
      float ta = ALPHA * (1.f - r2 * r2);
      float zeta = 1.f - ha[i] * ((d.x + EPS) / (fabsf(d.x) + EPS));
      float tb = w[i] / (zeta + EPS);
      f32x4 q0 = {c_, s_, ta * p.x - tb * p.y - p.x, tb * p.x + ta * p.y - p.y};
      f32x4 q1 = {d.x - DIFF, d.x + DIFF, d.y - DIFF, d.y + DIFF};
      st[s * 2 + 0] = q0;
      st[s * 2 + 1] = q1;
    }
    __syncthreads();

    // ---- scan chunk: 4 rotating buffers, distance-3 manual pipeline ----
    f32x4 A0, A1, A2, A3, B0, B1, B2, B3;
    f32x4 C0, C1, C2, C3, D0, D1, D2, D3;
    PRE(A, 0); PRE(B, 1); PRE(C, 2);
    for (int blk = 0; blk < CHUNK / 64; ++blk) {
      int pb = blk * 32;               // pair base within chunk
#pragma unroll
      for (int it8 = 0; it8 < 8; ++it8) {
        int p = pb + it8 * 4;
        int k0 = it8 * 8;              // compile-time local step base
        PRE(D, p + 3); W12; S2(A, k0 + 0); SBAR;
        PRE(A, p + 4); W12; S2(B, k0 + 2); SBAR;
        PRE(B, p + 5); W12; S2(C, k0 + 4); SBAR;
        PRE(C, p + 6); W12; S2(D, k0 + 6); SBAR;
        // wrap via &-mask at chunk end: stale reads land in regs that the
        // next chunk's prologue rewrites before any use.
      }
      // flush one 64-step block (coalesced, fused epilogue; vmcnt-only ops)
      float yn = fmaf(DT, cyk, yiC);
      float ang = fmaf(ampC, yn, bbC);
      out[tgt] = fminf(fmaxf(ang, -HB), HB);
      tgt += 64;
      int nb = (tgt < NN) ? tgt : (NN - 64 + lane);
      ampC = amp[nb]; bbC = bvec[nb]; yiC = xy2[nb].y;
    }
    W0;   // drain wrapped prefetches before refilling LDS
  }
}

extern "C" void kernel_launch(void* const* d_in, const int* in_sizes, int n_in,
                              void* d_out, int out_size, void* d_ws, size_t ws_size,
                              hipStream_t stream) {
  const float* phase = (const float*)d_in[0];
  const float* amp   = (const float*)d_in[1];
  const float* w     = (const float*)d_in[2];
  const float* ha    = (const float*)d_in[3];
  const float* b     = (const float*)d_in[4];
  const float* xy    = (const float*)d_in[5];
  const float* xydo  = (const float*)d_in[6];
  float* out = (float*)d_out;

  cpg_kernel<<<1, 64, 0, stream>>>(phase, amp, w, ha, b, xy, xydo, out);
}